// Round 17
// baseline (380.773 us; speedup 1.0000x reference)
//
#include <hip/hip_runtime.h>
#include <math.h>

// ---------------------------------------------------------------------------
// 3-layer GAT on MI355X — round 17: eighth-wave gatherx (8 edges per wave-load).
//   Evidence: gather time tracks EDGES not bytes (gatherx 64us @51MB vs
//   gather4f 86us @400MB).  x rows are 128B = 8 lanes x 16B, so 8 lane-groups
//   each own a different edge -> serial edge rounds per node drop ~8x.
//   Everything else = round 16.
// ---------------------------------------------------------------------------

#define LRELU_SLOPE 0.2f
#define MPAD 50048              // 391 * 128, padded row count for GEMM A tiles

typedef __attribute__((ext_vector_type(8))) short short8;
typedef __attribute__((ext_vector_type(4))) float f32x4;

__device__ __forceinline__ float bf2f(unsigned int u) {
    return __uint_as_float(u << 16);
}
__device__ __forceinline__ unsigned short f2bf(float f) {
    unsigned int u = __float_as_uint(f);
    unsigned int r = u + 0x7FFFu + ((u >> 16) & 1u);   // RNE
    return (unsigned short)(r >> 16);
}
__device__ __forceinline__ void load16_to_lds(const void* g, void* l) {
    __builtin_amdgcn_global_load_lds(
        (const __attribute__((address_space(1))) void*)g,
        (__attribute__((address_space(3))) void*)l, 16, 0, 0);
}
__device__ __forceinline__ float lrelu(float e) {
    return e > 0.f ? e : LRELU_SLOPE * e;
}

// ---------------- prep: casts + transposes + counts zero + ws fold ---------

__global__ __launch_bounds__(256) void prep_kernel(
    const float* __restrict__ x, const float* __restrict__ W1,
    const float* __restrict__ W2, const float* __restrict__ W3,
    const float* __restrict__ as1, const float* __restrict__ ad1,
    unsigned short* __restrict__ x_bf, unsigned short* __restrict__ W1t,
    unsigned short* __restrict__ W2t, unsigned short* __restrict__ W3t,
    int* __restrict__ counts, float* __restrict__ ws, int N)
{
    int i = blockIdx.x * 256 + threadIdx.x;
    const int nx = N * 64;
    if (i < nx) { x_bf[i] = f2bf(x[i]); return; }
    i -= nx;
    if (i < 64 * 512) {                    // W1 [64][512] -> W1t [512][64]
        int k = i / 512, nn = i % 512;
        W1t[nn * 64 + k] = f2bf(W1[i]);
        return;
    }
    i -= 64 * 512;
    if (i < 512 * 512) {                   // W2 [512][512] -> W2t [512][512]
        int k = i / 512, nn = i % 512;
        W2t[nn * 512 + k] = f2bf(W2[i]);
        return;
    }
    i -= 512 * 512;
    if (i < 512 * 128) {                   // W3 [512][128] -> W3t [128][512]
        int k = i / 128, nn = i % 128;
        W3t[(size_t)nn * 512 + k] = f2bf(W3[i]);
        return;
    }
    i -= 512 * 128;
    if (i < N) { counts[i] = 0; return; }
    i -= N;
    if (i < 256) {                         // ws fold: i = h*64+k, h<4
        int h = i >> 6, k = i & 63;
        float ss = 0.f, sd = 0.f;
        for (int c = 0; c < 128; ++c) {
            float wv = W1[k * 512 + h * 128 + c];
            ss += wv * as1[h * 128 + c];
            sd += wv * ad1[h * 128 + c];
        }
        ws[i] = ss;
        ws[256 + i] = sd;
    }
}

// ---------------- CSR build ----------------

__global__ void count_deg_kernel(const int* __restrict__ dst, int* __restrict__ counts, int E) {
    int e = blockIdx.x * blockDim.x + threadIdx.x;
    if (e < E) atomicAdd(&counts[dst[e]], 1);
}

__global__ __launch_bounds__(1024) void scan1_kernel(const int* __restrict__ counts,
                                                     int* __restrict__ row_ptr,
                                                     int* __restrict__ partial, int n) {
    __shared__ int wsum[16];
    const int t = threadIdx.x;
    const int lane = t & 63, w = t >> 6;
    const int i = blockIdx.x * 1024 + t;
    int v = (i < n) ? counts[i] : 0;
    int s = v;
    #pragma unroll
    for (int off = 1; off < 64; off <<= 1) {
        int u = __shfl_up(s, off);
        if (lane >= off) s += u;
    }
    if (lane == 63) wsum[w] = s;
    __syncthreads();
    if (w == 0 && lane < 16) {
        int tv = wsum[lane];
        #pragma unroll
        for (int off = 1; off < 16; off <<= 1) {
            int u = __shfl_up(tv, off);
            if (lane >= off) tv += u;
        }
        wsum[lane] = tv;
    }
    __syncthreads();
    int incl = s + (w > 0 ? wsum[w - 1] : 0);
    if (i < n) row_ptr[i + 1] = incl;
    if (t == 0) partial[blockIdx.x] = wsum[15];
}

__global__ void scan2_kernel(int* __restrict__ partial, int nb) {
    int lane = threadIdx.x;
    int v = (lane < nb) ? partial[lane] : 0;
    int s = v;
    #pragma unroll
    for (int off = 1; off < 64; off <<= 1) {
        int u = __shfl_up(s, off);
        if (lane >= off) s += u;
    }
    if (lane < nb) partial[lane] = s - v;
}

__global__ __launch_bounds__(1024) void scan3c_kernel(int* __restrict__ row_ptr,
                                                      const int* __restrict__ partial,
                                                      const int* __restrict__ counts,
                                                      int* __restrict__ cursor, int n) {
    const int i = blockIdx.x * 1024 + threadIdx.x;
    if (i < n) {
        int rp1 = row_ptr[i + 1] + partial[blockIdx.x];
        row_ptr[i + 1] = rp1;
        cursor[i] = rp1 - counts[i];
    }
    if (i == 0) row_ptr[0] = 0;
}

__global__ void fill_csr_kernel(const int* __restrict__ src, const int* __restrict__ dst,
                                int* __restrict__ cursor, int* __restrict__ csr_src, int E) {
    int e = blockIdx.x * blockDim.x + threadIdx.x;
    if (e < E) {
        int d = dst[e];
        int pos = atomicAdd(&cursor[d], 1);
        csr_src[pos] = src[e];
    }
}

// ---------------- layer-1 logits: als/ald from folded ws -------------------

__global__ __launch_bounds__(256) void als1_kernel(const float* __restrict__ x,
                                                   const float* __restrict__ ws,
                                                   float* __restrict__ als,
                                                   float* __restrict__ ald, int n_nodes) {
    const int lane = threadIdx.x & 63;
    const int wv = threadIdx.x >> 6;
    const int n = blockIdx.x * 4 + wv;
    if (n >= n_nodes) return;
    const float xv = x[(size_t)n * 64 + lane];
    float d0 = xv * ws[lane],        d1 = xv * ws[64 + lane];
    float d2 = xv * ws[128 + lane],  d3 = xv * ws[192 + lane];
    float e0 = xv * ws[256 + lane],  e1 = xv * ws[320 + lane];
    float e2 = xv * ws[384 + lane],  e3 = xv * ws[448 + lane];
    #pragma unroll
    for (int off = 32; off >= 1; off >>= 1) {
        d0 += __shfl_xor(d0, off); d1 += __shfl_xor(d1, off);
        d2 += __shfl_xor(d2, off); d3 += __shfl_xor(d3, off);
        e0 += __shfl_xor(e0, off); e1 += __shfl_xor(e1, off);
        e2 += __shfl_xor(e2, off); e3 += __shfl_xor(e3, off);
    }
    if (lane == 0) {
        float4 a = {d0, d1, d2, d3};
        float4 b = {e0, e1, e2, e3};
        *(float4*)&als[(size_t)n * 4] = a;
        *(float4*)&ald[(size_t)n * 4] = b;
    }
}

// ---------------- layer-1 gather: EIGHTH-wave, 8 edges per wave-load -------
// lane = (g = lane>>3 edge slot, j = lane&7 -> 16B chunk, channels j*8..+7).
// Per 8-edge chunk: lanes<8 load csr_src + compute float4 alpha; each group g
// gets its edge's (s, alpha4) via shfl; ONE wave-load covers 8 rows.
// acc[4 heads][8 ch] per lane; cross-group shfl_xor(8,16,32) reduce at end.

__global__ __launch_bounds__(256) void gatherx_kernel(
    const unsigned short* __restrict__ x_bf,    // [N, 64] bf16
    const float* __restrict__ als, const float* __restrict__ ald,
    const int* __restrict__ row_ptr, const int* __restrict__ csr_src,
    unsigned short* __restrict__ xagg,          // [MPAD, 256] bf16
    int n_nodes)
{
    const int lane = threadIdx.x & 63;
    const int wv = threadIdx.x >> 6;
    const int n = blockIdx.x * 4 + wv;
    if (n >= n_nodes) return;
    const int g = lane >> 3;      // edge slot 0..7
    const int j = lane & 7;       // 16B chunk (channels j*8..j*8+7)

    const int start = row_ptr[n];
    const int deg = row_ptr[n + 1] - start;
    const float4 aldv = *(const float4*)&ald[(size_t)n * 4];

    float acc[4][8] = {};
    float wsx = 0.f, wsy = 0.f, wsz = 0.f, wsw = 0.f;

    for (int base = 0; base < deg; base += 8) {
        const int cnt = min(8, deg - base);
        int s_l = 0;
        float ax_l = 0.f, ay_l = 0.f, az_l = 0.f, aw_l = 0.f;
        if (lane < cnt) {
            s_l = csr_src[start + base + lane];
            float4 a = *(const float4*)&als[(size_t)s_l * 4];
            ax_l = __expf(lrelu(a.x + aldv.x));
            ay_l = __expf(lrelu(a.y + aldv.y));
            az_l = __expf(lrelu(a.z + aldv.z));
            aw_l = __expf(lrelu(a.w + aldv.w));
            wsx += ax_l; wsy += ay_l; wsz += az_l; wsw += aw_l;
        }
        const int sg  = __shfl(s_l, g);
        const float a0 = __shfl(ax_l, g);
        const float a1 = __shfl(ay_l, g);
        const float a2 = __shfl(az_l, g);
        const float a3 = __shfl(aw_l, g);
        short8 v = *(const short8*)(x_bf + (size_t)sg * 64 + j * 8);
        #pragma unroll
        for (int c = 0; c < 8; ++c) {
            const float xv = bf2f((unsigned int)(unsigned short)v[c]);
            acc[0][c] += a0 * xv;
            acc[1][c] += a1 * xv;
            acc[2][c] += a2 * xv;
            acc[3][c] += a3 * xv;
        }
    }

    // wsum: lanes >=8 hold 0; full-wave butterfly gives totals everywhere
    #pragma unroll
    for (int off = 1; off < 64; off <<= 1) {
        wsx += __shfl_xor(wsx, off);
        wsy += __shfl_xor(wsy, off);
        wsz += __shfl_xor(wsz, off);
        wsw += __shfl_xor(wsw, off);
    }
    float sc[4];
    sc[0] = deg > 0 ? 1.f / wsx : 0.f;
    sc[1] = deg > 0 ? 1.f / wsy : 0.f;
    sc[2] = deg > 0 ? 1.f / wsz : 0.f;
    sc[3] = deg > 0 ? 1.f / wsw : 0.f;

    // reduce acc across the 8 edge-slot groups (lane bits 3,4,5)
    #pragma unroll
    for (int h = 0; h < 4; ++h)
        #pragma unroll
        for (int c = 0; c < 8; ++c) {
            acc[h][c] += __shfl_xor(acc[h][c], 8);
            acc[h][c] += __shfl_xor(acc[h][c], 16);
            acc[h][c] += __shfl_xor(acc[h][c], 32);
        }

    if (g == 0) {                 // lanes 0..7: write chunk j of all 4 heads
        #pragma unroll
        for (int h = 0; h < 4; ++h) {
            short8 o;
            #pragma unroll
            for (int c = 0; c < 8; ++c) o[c] = (short)f2bf(acc[h][c] * sc[h]);
            *(short8*)&xagg[(size_t)n * 256 + h * 64 + j * 8] = o;
        }
    }
}

// ---------------- layer-1 output GEMM: feat = ELU(xagg @ W1 + b1) ----------

__global__ __launch_bounds__(256) void gemm_out_kernel(
    const unsigned short* __restrict__ A,    // xagg [MPAD][256]
    const unsigned short* __restrict__ Bt,   // W1t [512][64]
    const float* __restrict__ bias,          // [512]
    unsigned short* __restrict__ Cout,       // feat [M][512]
    int M)
{
    __shared__ short As[2 * 128 * 32];
    __shared__ short Bs[2 * 128 * 32];
    const int t = threadIdx.x;
    const int w = t >> 6, lane = t & 63;
    const int wr = w >> 1, wc = w & 1;

    const int nwg = gridDim.x * gridDim.y;
    const int wg  = blockIdx.x + gridDim.x * blockIdx.y;
    const int qch = nwg >> 3, rch = nwg & 7;
    const int xcd = wg & 7, pos = wg >> 3;
    const int lg  = (xcd < rch ? xcd * (qch + 1) : rch * (qch + 1) + (xcd - rch) * qch) + pos;
    const int bx  = lg % gridDim.x;
    const int by  = lg / gridDim.x;

    const int rowBase = by * 128;
    const int head = bx;
    const int colBase = bx * 128;
    const int q = lane >> 4;
    const int r16 = lane & 15;
    const int qs = (q ^ ((r16 >> 1) & 3)) * 8;

    f32x4 acc[4][4] = {};

    const int sRow = t >> 2;
    const int sOff = ((t & 3) ^ ((sRow >> 1) & 3)) * 8;

    auto stage = [&](int kt, int b) {
        const int koff = kt * 32 + sOff;
        #pragma unroll
        for (int rr = 0; rr < 2; ++rr) {
            const unsigned short* gA = A + (size_t)(rowBase + rr * 64 + sRow) * 256 + head * 64 + koff;
            load16_to_lds(gA, (char*)As + b * 8192 + rr * 4096 + w * 1024);
            const unsigned short* gB = Bt + (size_t)(colBase + rr * 64 + sRow) * 64 + koff;
            load16_to_lds(gB, (char*)Bs + b * 8192 + rr * 4096 + w * 1024);
        }
    };

    stage(0, 0);
    __syncthreads();

    #pragma unroll
    for (int kt = 0; kt < 2; ++kt) {          // K = 64
        const int cur = kt & 1;
        if (kt + 1 < 2) stage(kt + 1, cur ^ 1);

        const short* Ab = As + cur * 4096;
        const short* Bb = Bs + cur * 4096;
        short8 af[4], bfr[4];
        #pragma unroll
        for (int m = 0; m < 4; ++m)
            af[m] = *(const short8*)&Ab[(wr * 64 + m * 16 + r16) * 32 + qs];
        #pragma unroll
        for (int n = 0; n < 4; ++n)
            bfr[n] = *(const short8*)&Bb[(wc * 64 + n * 16 + r16) * 32 + qs];
        #pragma unroll
        for (int m = 0; m < 4; ++m)
            #pragma unroll
            for (int n = 0; n < 4; ++n)
                acc[m][n] = __builtin_amdgcn_mfma_f32_16x16x32_bf16(af[m], bfr[n], acc[m][n], 0, 0, 0);

        __syncthreads();
    }

    float bv[4];
    #pragma unroll
    for (int n = 0; n < 4; ++n) bv[n] = bias[colBase + wc * 64 + n * 16 + r16];

    #pragma unroll
    for (int m = 0; m < 4; ++m) {
        #pragma unroll
        for (int r = 0; r < 4; ++r) {
            const int gr = rowBase + wr * 64 + m * 16 + q * 4 + r;
            if (gr < M) {
                #pragma unroll
                for (int n = 0; n < 4; ++n) {
                    float o = acc[m][n][r] + bv[n];
                    o = o > 0.f ? o : expm1f(o);
                    Cout[(size_t)gr * 512 + colBase + wc * 64 + n * 16 + r16] = f2bf(o);
                }
            }
        }
    }
}

// ---------------- main bf16 MFMA GEMM + fused alpha dots (atomic-free) -----

__global__ __launch_bounds__(256) void gemm_mfma_kernel(
    const unsigned short* __restrict__ A,    // [>=rowTiles*128, K] bf16
    const unsigned short* __restrict__ Bt,   // [N, K] bf16
    unsigned short* __restrict__ C,          // [M, N] bf16
    const float* __restrict__ a_src,
    const float* __restrict__ a_dst,
    float* __restrict__ als,                 // [M, H]
    float* __restrict__ ald,
    int M, int N, int K, int H)
{
    __shared__ short As[2 * 128 * 32];
    __shared__ short Bs[2 * 128 * 32];
    const int t = threadIdx.x;
    const int w = t >> 6, lane = t & 63;
    const int wr = w >> 1, wc = w & 1;

    const int nwg = gridDim.x * gridDim.y;
    const int wg  = blockIdx.x + gridDim.x * blockIdx.y;
    const int qch = nwg >> 3, rch = nwg & 7;
    const int xcd = wg & 7, pos = wg >> 3;
    const int lg  = (xcd < rch ? xcd * (qch + 1) : rch * (qch + 1) + (xcd - rch) * qch) + pos;
    const int bx  = lg % gridDim.x;
    const int by  = lg / gridDim.x;

    const int rowBase = by * 128;
    const int colBase = bx * 128;
    const int q = lane >> 4;
    const int r16 = lane & 15;
    const int qs = (q ^ ((r16 >> 1) & 3)) * 8;

    f32x4 acc[4][4] = {};

    const int sRow = t >> 2;
    const int sOff = ((t & 3) ^ ((sRow >> 1) & 3)) * 8;

    const int NT = K >> 5;
    auto stage = [&](int kt, int b) {
        const int koff = kt * 32 + sOff;
        #pragma unroll
        for (int rr = 0; rr < 2; ++rr) {
            const unsigned short* gA = A + (size_t)(rowBase + rr * 64 + sRow) * K + koff;
            load16_to_lds(gA, (char*)As + b * 8192 + rr * 4096 + w * 1024);
            const unsigned short* gB = Bt + (size_t)(colBase + rr * 64 + sRow) * K + koff;
            load16_to_lds(gB, (char*)Bs + b * 8192 + rr * 4096 + w * 1024);
        }
    };

    stage(0, 0);
    __syncthreads();

    for (int kt = 0; kt < NT; ++kt) {
        const int cur = kt & 1;
        if (kt + 1 < NT) stage(kt + 1, cur ^ 1);

        const short* Ab = As + cur * 4096;
        const short* Bb = Bs + cur * 4096;
        short8 af[4], bfr[4];
        #pragma unroll
        for (int m = 0; m < 4; ++m)
            af[m] = *(const short8*)&Ab[(wr * 64 + m * 16 + r16) * 32 + qs];
        #pragma unroll
        for (int n = 0; n < 4; ++n)
            bfr[n] = *(const short8*)&Bb[(wc * 64 + n * 16 + r16) * 32 + qs];
        #pragma unroll
        for (int m = 0; m < 4; ++m)
            #pragma unroll
            for (int n = 0; n < 4; ++n)
                acc[m][n] = __builtin_amdgcn_mfma_f32_16x16x32_bf16(af[m], bfr[n], acc[m][n], 0, 0, 0);

        __syncthreads();
    }

    float asv[4], adv[4];
    #pragma unroll
    for (int n = 0; n < 4; ++n) {
        int col = colBase + wc * 64 + n * 16 + r16;
        asv[n] = a_src[col];
        adv[n] = a_dst[col];
    }
    const int head = bx;

    float* red = (float*)As;

    #pragma unroll
    for (int m = 0; m < 4; ++m) {
        #pragma unroll
        for (int r = 0; r < 4; ++r) {
            const int rowl = wr * 64 + m * 16 + q * 4 + r;
            const int gr = rowBase + rowl;
            float ps = 0.f, pd = 0.f;
            #pragma unroll
            for (int n = 0; n < 4; ++n) {
                ps += acc[m][n][r] * asv[n];
                pd += acc[m][n][r] * adv[n];
            }
            #pragma unroll
            for (int off = 8; off >= 1; off >>= 1) {
                ps += __shfl_xor(ps, off);
                pd += __shfl_xor(pd, off);
            }
            if (r16 == 0) {
                red[wc * 128 + rowl] = ps;
                red[256 + wc * 128 + rowl] = pd;
            }
            if (gr < M) {
                #pragma unroll
                for (int n = 0; n < 4; ++n)
                    C[(size_t)gr * N + colBase + wc * 64 + n * 16 + r16] = f2bf(acc[m][n][r]);
            }
        }
    }
    __syncthreads();
    if (t < 128) {
        const int gr = rowBase + t;
        if (gr < M) {
            als[(size_t)gr * H + head] = red[t] + red[128 + t];
            ald[(size_t)gr * H + head] = red[256 + t] + red[384 + t];
        }
    }
}

// ---------------- fused gather (H=4): depth-2 pipeline ----------------------

__global__ __launch_bounds__(256) void gather4f_kernel(
    const unsigned short* __restrict__ hfeat,   // [N, 512] bf16
    const float* __restrict__ als, const float* __restrict__ ald,
    const int* __restrict__ row_ptr, const int* __restrict__ csr_src,
    const float* __restrict__ bias, unsigned short* __restrict__ out,
    int n_nodes)
{
    const int lane = threadIdx.x & 63;
    const int wv = threadIdx.x >> 6;
    const int n = blockIdx.x * 4 + wv;
    if (n >= n_nodes) return;
    const int head = lane >> 4;
    const int li = lane & 15;
    const int grpBase = lane & ~15;

    const int start = row_ptr[n];
    const int deg = row_ptr[n + 1] - start;
    const float aldv = ald[(size_t)n * 4 + head];

    float acc[8] = {};
    float wsum = 0.f;
    for (int base = 0; base < deg; base += 16) {
        const int cnt = min(16, deg - base);
        int s_l = 0; float w_l = 0.f;
        if (li < cnt) {
            s_l = csr_src[start + base + li];
            float e = als[(size_t)s_l * 4 + head] + aldv;
            w_l = __expf(lrelu(e));
            wsum += w_l;
        }
        // depth-2 pipeline: prefetch edge 0, issue e+1 before consuming e
        int sP = __shfl(s_l, grpBase);
        float aP = __shfl(w_l, grpBase);
        short8 vP = *(const short8*)(hfeat + (size_t)sP * 512 + lane * 8);
        for (int e = 0; e < cnt; ++e) {
            const int nidx = (e + 1 < cnt) ? e + 1 : e;
            const int sN = __shfl(s_l, grpBase + nidx);
            const float aN = __shfl(w_l, grpBase + nidx);
            short8 vN = *(const short8*)(hfeat + (size_t)sN * 512 + lane * 8);
            #pragma unroll
            for (int j = 0; j < 8; ++j)
                acc[j] += aP * bf2f((unsigned int)(unsigned short)vP[j]);
            vP = vN; aP = aN;
        }
    }

    #pragma unroll
    for (int off = 8; off >= 1; off >>= 1) wsum += __shfl_xor(wsum, off);
    const float sc = (deg > 0) ? 1.f / wsum : 0.f;

    float ov[8];
    #pragma unroll
    for (int j = 0; j < 8; ++j) {
        float o = acc[j] * sc + bias[lane * 8 + j];
        ov[j] = o > 0.f ? o : expm1f(o);
    }
    short8 v;
    #pragma unroll
    for (int j = 0; j < 8; ++j) v[j] = (short)f2bf(ov[j]);
    *(short8*)&out[(size_t)n * 512 + lane * 8] = v;
}

// ---------------- fused gather (H=1): quarter-wave, depth-2 pipeline -------

__global__ __launch_bounds__(256) void gather1f_kernel(
    const unsigned short* __restrict__ hfeat,   // [N, 128] bf16
    const float* __restrict__ als, const float* __restrict__ ald,
    const int* __restrict__ row_ptr, const int* __restrict__ csr_src,
    const float* __restrict__ bias, float* __restrict__ out, int n_nodes)
{
    const int lane = threadIdx.x & 63;
    const int wv = threadIdx.x >> 6;
    const int n = blockIdx.x * 4 + wv;
    if (n >= n_nodes) return;
    const int qid = lane >> 4;       // quarter 0..3 = edge slot
    const int ql = lane & 15;        // 16B slot within row

    const int start = row_ptr[n];
    const int deg = row_ptr[n + 1] - start;
    const float aldv = ald[n];

    float acc[8] = {};
    float wsum = 0.f;
    for (int base = 0; base < deg; base += 64) {
        const int cnt = min(64, deg - base);
        int s_l = 0; float w_l = 0.f;
        if (lane < cnt) {
            s_l = csr_src[start + base + lane];
            float e = als[s_l] + aldv;
            w_l = __expf(lrelu(e));
            wsum += w_l;
        }
        // depth-2 pipeline over the e+=4 quarter-wave slots
        int idx = qid;
        int idxc = idx < cnt ? idx : 0;
        int sP = __shfl(s_l, idxc);
        float awP = __shfl(w_l, idxc);
        float aP = idx < cnt ? awP : 0.f;
        short8 vP = *(const short8*)(hfeat + (size_t)sP * 128 + ql * 8);
        for (int e = 0; e < cnt; e += 4) {
            const int nidxRaw = e + 4 + qid;
            const int nidxc = nidxRaw < cnt ? nidxRaw : 0;
            const int sN = __shfl(s_l, nidxc);
            const float awN = __shfl(w_l, nidxc);
            const float aN = nidxRaw < cnt ? awN : 0.f;
            short8 vN = *(const short8*)(hfeat + (size_t)sN * 128 + ql * 8);
            #pragma unroll
            for (int j = 0; j < 8; ++j)
                acc[j] += aP * bf2f((unsigned int)(unsigned short)vP[j]);
            vP = vN; aP = aN;
        }
    }

    #pragma unroll
    for (int off = 32; off >= 1; off >>= 1) wsum += __shfl_xor(wsum, off);
    const float sc = (deg > 0) ? 1.f / wsum : 0.f;

    #pragma unroll
    for (int j = 0; j < 8; ++j) {
        acc[j] += __shfl_xor(acc[j], 16);
        acc[j] += __shfl_xor(acc[j], 32);
    }

    if (qid == 0) {
        float tmp[8];
        #pragma unroll
        for (int j = 0; j < 8; ++j) {
            float o = acc[j] * sc + bias[ql * 8 + j];
            tmp[j] = o > 0.f ? o : expm1f(o);
        }
        float4 o0 = {tmp[0], tmp[1], tmp[2], tmp[3]};
        float4 o1 = {tmp[4], tmp[5], tmp[6], tmp[7]};
        float* op = out + (size_t)n * 128 + ql * 8;
        *(float4*)op = o0;
        *(float4*)(op + 4) = o1;
    }
}

// ---------------------------------------------------------------------------

extern "C" void kernel_launch(void* const* d_in, const int* in_sizes, int n_in,
                              void* d_out, int out_size, void* d_ws, size_t ws_size,
                              hipStream_t stream) {
    const float* x   = (const float*)d_in[0];
    const int*   ei  = (const int*)d_in[1];
    const float* W1  = (const float*)d_in[2];
    const float* as1 = (const float*)d_in[3];
    const float* ad1 = (const float*)d_in[4];
    const float* b1  = (const float*)d_in[5];
    const float* W2  = (const float*)d_in[6];
    const float* as2 = (const float*)d_in[7];
    const float* ad2 = (const float*)d_in[8];
    const float* b2  = (const float*)d_in[9];
    const float* W3  = (const float*)d_in[10];
    const float* as3 = (const float*)d_in[11];
    const float* ad3 = (const float*)d_in[12];
    const float* b3  = (const float*)d_in[13];

    const int N = in_sizes[0] / 64;      // 50000
    const int E = in_sizes[1] / 2;       // 400000
    const int HC = 512;

    const int* src = ei;
    const int* dst = ei + E;

    size_t off = 0;
    auto carve = [&](size_t bytes) -> void* {
        void* p = (char*)d_ws + off;
        off += (bytes + 255) & ~(size_t)255;
        return p;
    };
    unsigned short* x_bf    = (unsigned short*)carve((size_t)MPAD * 64 * 2);
    unsigned short* feat_bf = (unsigned short*)carve((size_t)MPAD * HC * 2);
    unsigned short* h_bf    = (unsigned short*)carve((size_t)N * HC * 2);
    unsigned short* xagg    = (unsigned short*)carve((size_t)MPAD * 256 * 2);
    unsigned short* W1t     = (unsigned short*)carve((size_t)512 * 64 * 2);
    unsigned short* W2t     = (unsigned short*)carve((size_t)512 * 512 * 2);
    unsigned short* W3t     = (unsigned short*)carve((size_t)128 * 512 * 2);
    float* stats  = (float*)carve((size_t)N * 8 * sizeof(float));   // als|ald
    float* als    = stats;
    float* ald    = stats + (size_t)N * 4;
    float* ws     = (float*)carve(512 * sizeof(float) * 2);
    int*   counts = (int*)carve((size_t)N * sizeof(int));
    int*   row_ptr= (int*)carve((size_t)(N + 1) * sizeof(int));
    int*   cursor = (int*)carve((size_t)N * sizeof(int));
    int*   csr_src= (int*)carve((size_t)E * sizeof(int));
    int*   partial= (int*)carve(64 * sizeof(int));
    (void)ws_size;

    const int nb = (N + 1023) / 1024;    // 49 <= 64
    const int prepTotal = N * 64 + 64 * 512 + 512 * 512 + 512 * 128 + N + 256;

    // ---- prep (casts + transposes + counts zero + ws fold) ----
    prep_kernel<<<(prepTotal + 255) / 256, 256, 0, stream>>>(
        x, W1, W2, W3, as1, ad1, x_bf, W1t, W2t, W3t, counts, ws, N);

    // ---- CSR build ----
    count_deg_kernel<<<(E + 255) / 256, 256, 0, stream>>>(dst, counts, E);
    scan1_kernel<<<nb, 1024, 0, stream>>>(counts, row_ptr, partial, N);
    scan2_kernel<<<1, 64, 0, stream>>>(partial, nb);
    scan3c_kernel<<<nb, 1024, 0, stream>>>(row_ptr, partial, counts, cursor, N);
    fill_csr_kernel<<<(E + 255) / 256, 256, 0, stream>>>(src, dst, cursor, csr_src, E);

    const int rowTiles = (N + 127) / 128;   // 391
    const int aggBlocks = (N + 3) / 4;

    // ---- layer 1 (aggregate x, then transform) ----
    als1_kernel<<<aggBlocks, 256, 0, stream>>>(x, ws, als, ald, N);
    gatherx_kernel<<<aggBlocks, 256, 0, stream>>>(x_bf, als, ald, row_ptr, csr_src, xagg, N);
    gemm_out_kernel<<<dim3(4, rowTiles), 256, 0, stream>>>(xagg, W1t, b1, feat_bf, N);

    // ---- layer 2 ----
    gemm_mfma_kernel<<<dim3(4, rowTiles), 256, 0, stream>>>(feat_bf, W2t, h_bf, as2, ad2,
                                                            als, ald, N, 512, 512, 4);
    gather4f_kernel<<<aggBlocks, 256, 0, stream>>>(h_bf, als, ald, row_ptr, csr_src,
                                                   b2, feat_bf, N);

    // ---- layer 3 ----
    gemm_mfma_kernel<<<dim3(1, rowTiles), 256, 0, stream>>>(feat_bf, W3t, h_bf, as3, ad3,
                                                            als, ald, N, 128, 512, 1);
    gather1f_kernel<<<aggBlocks, 256, 0, stream>>>(h_bf, als, ald, row_ptr, csr_src,
                                                   b3, (float*)d_out, N);
}

// Round 18
// 349.201 us; speedup vs baseline: 1.0904x; 1.0904x over previous
//
#include <hip/hip_runtime.h>
#include <math.h>

// ---------------------------------------------------------------------------
// 3-layer GAT on MI355X — round 18: LOCK-IN of best config (round 15, 350.6us)
//   + scan2 folded into scan3 (one fewer dispatch).
//   gatherx reverted to the sixteenth-lane serial form (R17 eighth-wave
//   regressed +29us: reduction-tail/VGPR cost).  gather structure is at its
//   measured floor: 5 variants all 85-87us, invariant to MLP/bytes/weights.
// ---------------------------------------------------------------------------

#define LRELU_SLOPE 0.2f
#define MPAD 50048              // 391 * 128, padded row count for GEMM A tiles

typedef __attribute__((ext_vector_type(8))) short short8;
typedef __attribute__((ext_vector_type(4))) float f32x4;

__device__ __forceinline__ float bf2f(unsigned int u) {
    return __uint_as_float(u << 16);
}
__device__ __forceinline__ unsigned short f2bf(float f) {
    unsigned int u = __float_as_uint(f);
    unsigned int r = u + 0x7FFFu + ((u >> 16) & 1u);   // RNE
    return (unsigned short)(r >> 16);
}
__device__ __forceinline__ void load16_to_lds(const void* g, void* l) {
    __builtin_amdgcn_global_load_lds(
        (const __attribute__((address_space(1))) void*)g,
        (__attribute__((address_space(3))) void*)l, 16, 0, 0);
}
__device__ __forceinline__ float lrelu(float e) {
    return e > 0.f ? e : LRELU_SLOPE * e;
}

// ---------------- prep: casts + transposes + counts zero + ws fold ---------

__global__ __launch_bounds__(256) void prep_kernel(
    const float* __restrict__ x, const float* __restrict__ W1,
    const float* __restrict__ W2, const float* __restrict__ W3,
    const float* __restrict__ as1, const float* __restrict__ ad1,
    unsigned short* __restrict__ x_bf, unsigned short* __restrict__ W1t,
    unsigned short* __restrict__ W2t, unsigned short* __restrict__ W3t,
    int* __restrict__ counts, float* __restrict__ ws, int N)
{
    int i = blockIdx.x * 256 + threadIdx.x;
    const int nx = N * 64;
    if (i < nx) { x_bf[i] = f2bf(x[i]); return; }
    i -= nx;
    if (i < 64 * 512) {                    // W1 [64][512] -> W1t [512][64]
        int k = i / 512, nn = i % 512;
        W1t[nn * 64 + k] = f2bf(W1[i]);
        return;
    }
    i -= 64 * 512;
    if (i < 512 * 512) {                   // W2 [512][512] -> W2t [512][512]
        int k = i / 512, nn = i % 512;
        W2t[nn * 512 + k] = f2bf(W2[i]);
        return;
    }
    i -= 512 * 512;
    if (i < 512 * 128) {                   // W3 [512][128] -> W3t [128][512]
        int k = i / 128, nn = i % 128;
        W3t[(size_t)nn * 512 + k] = f2bf(W3[i]);
        return;
    }
    i -= 512 * 128;
    if (i < N) { counts[i] = 0; return; }
    i -= N;
    if (i < 256) {                         // ws fold: i = h*64+k, h<4
        int h = i >> 6, k = i & 63;
        float ss = 0.f, sd = 0.f;
        for (int c = 0; c < 128; ++c) {
            float wv = W1[k * 512 + h * 128 + c];
            ss += wv * as1[h * 128 + c];
            sd += wv * ad1[h * 128 + c];
        }
        ws[i] = ss;
        ws[256 + i] = sd;
    }
}

// ---------------- CSR build ----------------

__global__ void count_deg_kernel(const int* __restrict__ dst, int* __restrict__ counts, int E) {
    int e = blockIdx.x * blockDim.x + threadIdx.x;
    if (e < E) atomicAdd(&counts[dst[e]], 1);
}

__global__ __launch_bounds__(1024) void scan1_kernel(const int* __restrict__ counts,
                                                     int* __restrict__ row_ptr,
                                                     int* __restrict__ partial, int n) {
    __shared__ int wsum[16];
    const int t = threadIdx.x;
    const int lane = t & 63, w = t >> 6;
    const int i = blockIdx.x * 1024 + t;
    int v = (i < n) ? counts[i] : 0;
    int s = v;
    #pragma unroll
    for (int off = 1; off < 64; off <<= 1) {
        int u = __shfl_up(s, off);
        if (lane >= off) s += u;
    }
    if (lane == 63) wsum[w] = s;
    __syncthreads();
    if (w == 0 && lane < 16) {
        int tv = wsum[lane];
        #pragma unroll
        for (int off = 1; off < 16; off <<= 1) {
            int u = __shfl_up(tv, off);
            if (lane >= off) tv += u;
        }
        wsum[lane] = tv;
    }
    __syncthreads();
    int incl = s + (w > 0 ? wsum[w - 1] : 0);
    if (i < n) row_ptr[i + 1] = incl;
    if (t == 0) partial[blockIdx.x] = wsum[15];
}

// scan3 with inline exclusive-scan of partial (scan2 folded in) + cursor init
__global__ __launch_bounds__(1024) void scan3c_kernel(int* __restrict__ row_ptr,
                                                      const int* __restrict__ partial,
                                                      const int* __restrict__ counts,
                                                      int* __restrict__ cursor,
                                                      int n, int nb) {
    __shared__ int ex[64];
    if (threadIdx.x < 64) {
        const int lane = threadIdx.x;
        int v = (lane < nb) ? partial[lane] : 0;
        int s = v;
        #pragma unroll
        for (int off = 1; off < 64; off <<= 1) {
            int u = __shfl_up(s, off);
            if (lane >= off) s += u;
        }
        ex[lane] = s - v;
    }
    __syncthreads();
    const int i = blockIdx.x * 1024 + threadIdx.x;
    if (i < n) {
        int rp1 = row_ptr[i + 1] + ex[blockIdx.x];
        row_ptr[i + 1] = rp1;
        cursor[i] = rp1 - counts[i];
    }
    if (i == 0) row_ptr[0] = 0;
}

__global__ void fill_csr_kernel(const int* __restrict__ src, const int* __restrict__ dst,
                                int* __restrict__ cursor, int* __restrict__ csr_src, int E) {
    int e = blockIdx.x * blockDim.x + threadIdx.x;
    if (e < E) {
        int d = dst[e];
        int pos = atomicAdd(&cursor[d], 1);
        csr_src[pos] = src[e];
    }
}

// ---------------- layer-1 logits: als/ald from folded ws -------------------

__global__ __launch_bounds__(256) void als1_kernel(const float* __restrict__ x,
                                                   const float* __restrict__ ws,
                                                   float* __restrict__ als,
                                                   float* __restrict__ ald, int n_nodes) {
    const int lane = threadIdx.x & 63;
    const int wv = threadIdx.x >> 6;
    const int n = blockIdx.x * 4 + wv;
    if (n >= n_nodes) return;
    const float xv = x[(size_t)n * 64 + lane];
    float d0 = xv * ws[lane],        d1 = xv * ws[64 + lane];
    float d2 = xv * ws[128 + lane],  d3 = xv * ws[192 + lane];
    float e0 = xv * ws[256 + lane],  e1 = xv * ws[320 + lane];
    float e2 = xv * ws[384 + lane],  e3 = xv * ws[448 + lane];
    #pragma unroll
    for (int off = 32; off >= 1; off >>= 1) {
        d0 += __shfl_xor(d0, off); d1 += __shfl_xor(d1, off);
        d2 += __shfl_xor(d2, off); d3 += __shfl_xor(d3, off);
        e0 += __shfl_xor(e0, off); e1 += __shfl_xor(e1, off);
        e2 += __shfl_xor(e2, off); e3 += __shfl_xor(e3, off);
    }
    if (lane == 0) {
        float4 a = {d0, d1, d2, d3};
        float4 b = {e0, e1, e2, e3};
        *(float4*)&als[(size_t)n * 4] = a;
        *(float4*)&ald[(size_t)n * 4] = b;
    }
}

// ---------------- layer-1 gather: aggregate x, 16-lane head groups ---------

__global__ __launch_bounds__(256) void gatherx_kernel(
    const unsigned short* __restrict__ x_bf,    // [N, 64] bf16
    const float* __restrict__ als, const float* __restrict__ ald,
    const int* __restrict__ row_ptr, const int* __restrict__ csr_src,
    unsigned short* __restrict__ xagg,          // [MPAD, 256] bf16
    int n_nodes)
{
    const int lane = threadIdx.x & 63;
    const int wv = threadIdx.x >> 6;
    const int n = blockIdx.x * 4 + wv;
    if (n >= n_nodes) return;
    const int head = lane >> 4;
    const int li = lane & 15;
    const int grpBase = lane & ~15;

    const int start = row_ptr[n];
    const int deg = row_ptr[n + 1] - start;
    const float aldv = ald[(size_t)n * 4 + head];

    float acc[4] = {};
    float wsum = 0.f;
    for (int base = 0; base < deg; base += 16) {
        const int cnt = min(16, deg - base);
        int s_l = 0; float w_l = 0.f;
        if (li < cnt) {
            s_l = csr_src[start + base + li];
            w_l = __expf(lrelu(als[(size_t)s_l * 4 + head] + aldv));
            wsum += w_l;
        }
        for (int e = 0; e < cnt; ++e) {
            const int s = __shfl(s_l, grpBase + e);
            const float a = __shfl(w_l, grpBase + e);
            uint2 v = *(const uint2*)(x_bf + (size_t)s * 64 + li * 4);
            acc[0] += a * bf2f(v.x & 0xFFFFu);
            acc[1] += a * bf2f(v.x >> 16);
            acc[2] += a * bf2f(v.y & 0xFFFFu);
            acc[3] += a * bf2f(v.y >> 16);
        }
    }

    #pragma unroll
    for (int off = 8; off >= 1; off >>= 1) wsum += __shfl_xor(wsum, off);
    const float sc = (deg > 0) ? 1.f / wsum : 0.f;

    uint2 o;
    o.x = (unsigned int)f2bf(acc[0] * sc) | ((unsigned int)f2bf(acc[1] * sc) << 16);
    o.y = (unsigned int)f2bf(acc[2] * sc) | ((unsigned int)f2bf(acc[3] * sc) << 16);
    *(uint2*)&xagg[(size_t)n * 256 + head * 64 + li * 4] = o;
}

// ---------------- layer-1 output GEMM: feat = ELU(xagg @ W1 + b1) ----------

__global__ __launch_bounds__(256) void gemm_out_kernel(
    const unsigned short* __restrict__ A,    // xagg [MPAD][256]
    const unsigned short* __restrict__ Bt,   // W1t [512][64]
    const float* __restrict__ bias,          // [512]
    unsigned short* __restrict__ Cout,       // feat [M][512]
    int M)
{
    __shared__ short As[2 * 128 * 32];
    __shared__ short Bs[2 * 128 * 32];
    const int t = threadIdx.x;
    const int w = t >> 6, lane = t & 63;
    const int wr = w >> 1, wc = w & 1;

    const int nwg = gridDim.x * gridDim.y;
    const int wg  = blockIdx.x + gridDim.x * blockIdx.y;
    const int qch = nwg >> 3, rch = nwg & 7;
    const int xcd = wg & 7, pos = wg >> 3;
    const int lg  = (xcd < rch ? xcd * (qch + 1) : rch * (qch + 1) + (xcd - rch) * qch) + pos;
    const int bx  = lg % gridDim.x;
    const int by  = lg / gridDim.x;

    const int rowBase = by * 128;
    const int head = bx;
    const int colBase = bx * 128;
    const int q = lane >> 4;
    const int r16 = lane & 15;
    const int qs = (q ^ ((r16 >> 1) & 3)) * 8;

    f32x4 acc[4][4] = {};

    const int sRow = t >> 2;
    const int sOff = ((t & 3) ^ ((sRow >> 1) & 3)) * 8;

    auto stage = [&](int kt, int b) {
        const int koff = kt * 32 + sOff;
        #pragma unroll
        for (int rr = 0; rr < 2; ++rr) {
            const unsigned short* gA = A + (size_t)(rowBase + rr * 64 + sRow) * 256 + head * 64 + koff;
            load16_to_lds(gA, (char*)As + b * 8192 + rr * 4096 + w * 1024);
            const unsigned short* gB = Bt + (size_t)(colBase + rr * 64 + sRow) * 64 + koff;
            load16_to_lds(gB, (char*)Bs + b * 8192 + rr * 4096 + w * 1024);
        }
    };

    stage(0, 0);
    __syncthreads();

    #pragma unroll
    for (int kt = 0; kt < 2; ++kt) {          // K = 64
        const int cur = kt & 1;
        if (kt + 1 < 2) stage(kt + 1, cur ^ 1);

        const short* Ab = As + cur * 4096;
        const short* Bb = Bs + cur * 4096;
        short8 af[4], bfr[4];
        #pragma unroll
        for (int m = 0; m < 4; ++m)
            af[m] = *(const short8*)&Ab[(wr * 64 + m * 16 + r16) * 32 + qs];
        #pragma unroll
        for (int n = 0; n < 4; ++n)
            bfr[n] = *(const short8*)&Bb[(wc * 64 + n * 16 + r16) * 32 + qs];
        #pragma unroll
        for (int m = 0; m < 4; ++m)
            #pragma unroll
            for (int n = 0; n < 4; ++n)
                acc[m][n] = __builtin_amdgcn_mfma_f32_16x16x32_bf16(af[m], bfr[n], acc[m][n], 0, 0, 0);

        __syncthreads();
    }

    float bv[4];
    #pragma unroll
    for (int n = 0; n < 4; ++n) bv[n] = bias[colBase + wc * 64 + n * 16 + r16];

    #pragma unroll
    for (int m = 0; m < 4; ++m) {
        #pragma unroll
        for (int r = 0; r < 4; ++r) {
            const int gr = rowBase + wr * 64 + m * 16 + q * 4 + r;
            if (gr < M) {
                #pragma unroll
                for (int n = 0; n < 4; ++n) {
                    float o = acc[m][n][r] + bv[n];
                    o = o > 0.f ? o : expm1f(o);
                    Cout[(size_t)gr * 512 + colBase + wc * 64 + n * 16 + r16] = f2bf(o);
                }
            }
        }
    }
}

// ---------------- main bf16 MFMA GEMM + fused alpha dots (atomic-free) -----

__global__ __launch_bounds__(256) void gemm_mfma_kernel(
    const unsigned short* __restrict__ A,    // [>=rowTiles*128, K] bf16
    const unsigned short* __restrict__ Bt,   // [N, K] bf16
    unsigned short* __restrict__ C,          // [M, N] bf16
    const float* __restrict__ a_src,
    const float* __restrict__ a_dst,
    float* __restrict__ als,                 // [M, H]
    float* __restrict__ ald,
    int M, int N, int K, int H)
{
    __shared__ short As[2 * 128 * 32];
    __shared__ short Bs[2 * 128 * 32];
    const int t = threadIdx.x;
    const int w = t >> 6, lane = t & 63;
    const int wr = w >> 1, wc = w & 1;

    const int nwg = gridDim.x * gridDim.y;
    const int wg  = blockIdx.x + gridDim.x * blockIdx.y;
    const int qch = nwg >> 3, rch = nwg & 7;
    const int xcd = wg & 7, pos = wg >> 3;
    const int lg  = (xcd < rch ? xcd * (qch + 1) : rch * (qch + 1) + (xcd - rch) * qch) + pos;
    const int bx  = lg % gridDim.x;
    const int by  = lg / gridDim.x;

    const int rowBase = by * 128;
    const int colBase = bx * 128;
    const int q = lane >> 4;
    const int r16 = lane & 15;
    const int qs = (q ^ ((r16 >> 1) & 3)) * 8;

    f32x4 acc[4][4] = {};

    const int sRow = t >> 2;
    const int sOff = ((t & 3) ^ ((sRow >> 1) & 3)) * 8;

    const int NT = K >> 5;
    auto stage = [&](int kt, int b) {
        const int koff = kt * 32 + sOff;
        #pragma unroll
        for (int rr = 0; rr < 2; ++rr) {
            const unsigned short* gA = A + (size_t)(rowBase + rr * 64 + sRow) * K + koff;
            load16_to_lds(gA, (char*)As + b * 8192 + rr * 4096 + w * 1024);
            const unsigned short* gB = Bt + (size_t)(colBase + rr * 64 + sRow) * K + koff;
            load16_to_lds(gB, (char*)Bs + b * 8192 + rr * 4096 + w * 1024);
        }
    };

    stage(0, 0);
    __syncthreads();

    for (int kt = 0; kt < NT; ++kt) {
        const int cur = kt & 1;
        if (kt + 1 < NT) stage(kt + 1, cur ^ 1);

        const short* Ab = As + cur * 4096;
        const short* Bb = Bs + cur * 4096;
        short8 af[4], bfr[4];
        #pragma unroll
        for (int m = 0; m < 4; ++m)
            af[m] = *(const short8*)&Ab[(wr * 64 + m * 16 + r16) * 32 + qs];
        #pragma unroll
        for (int n = 0; n < 4; ++n)
            bfr[n] = *(const short8*)&Bb[(wc * 64 + n * 16 + r16) * 32 + qs];
        #pragma unroll
        for (int m = 0; m < 4; ++m)
            #pragma unroll
            for (int n = 0; n < 4; ++n)
                acc[m][n] = __builtin_amdgcn_mfma_f32_16x16x32_bf16(af[m], bfr[n], acc[m][n], 0, 0, 0);

        __syncthreads();
    }

    float asv[4], adv[4];
    #pragma unroll
    for (int n = 0; n < 4; ++n) {
        int col = colBase + wc * 64 + n * 16 + r16;
        asv[n] = a_src[col];
        adv[n] = a_dst[col];
    }
    const int head = bx;

    float* red = (float*)As;

    #pragma unroll
    for (int m = 0; m < 4; ++m) {
        #pragma unroll
        for (int r = 0; r < 4; ++r) {
            const int rowl = wr * 64 + m * 16 + q * 4 + r;
            const int gr = rowBase + rowl;
            float ps = 0.f, pd = 0.f;
            #pragma unroll
            for (int n = 0; n < 4; ++n) {
                ps += acc[m][n][r] * asv[n];
                pd += acc[m][n][r] * adv[n];
            }
            #pragma unroll
            for (int off = 8; off >= 1; off >>= 1) {
                ps += __shfl_xor(ps, off);
                pd += __shfl_xor(pd, off);
            }
            if (r16 == 0) {
                red[wc * 128 + rowl] = ps;
                red[256 + wc * 128 + rowl] = pd;
            }
            if (gr < M) {
                #pragma unroll
                for (int n = 0; n < 4; ++n)
                    C[(size_t)gr * N + colBase + wc * 64 + n * 16 + r16] = f2bf(acc[m][n][r]);
            }
        }
    }
    __syncthreads();
    if (t < 128) {
        const int gr = rowBase + t;
        if (gr < M) {
            als[(size_t)gr * H + head] = red[t] + red[128 + t];
            ald[(size_t)gr * H + head] = red[256 + t] + red[384 + t];
        }
    }
}

// ---------------- fused gather (H=4): weights in-loop, one wave per node ---

__global__ __launch_bounds__(256) void gather4f_kernel(
    const unsigned short* __restrict__ hfeat,   // [N, 512] bf16
    const float* __restrict__ als, const float* __restrict__ ald,
    const int* __restrict__ row_ptr, const int* __restrict__ csr_src,
    const float* __restrict__ bias, unsigned short* __restrict__ out,
    int n_nodes)
{
    const int lane = threadIdx.x & 63;
    const int wv = threadIdx.x >> 6;
    const int n = blockIdx.x * 4 + wv;
    if (n >= n_nodes) return;
    const int head = lane >> 4;
    const int li = lane & 15;
    const int grpBase = lane & ~15;

    const int start = row_ptr[n];
    const int deg = row_ptr[n + 1] - start;
    const float aldv = ald[(size_t)n * 4 + head];

    float acc[8] = {};
    float wsum = 0.f;
    for (int base = 0; base < deg; base += 16) {
        const int cnt = min(16, deg - base);
        int s_l = 0; float w_l = 0.f;
        if (li < cnt) {
            s_l = csr_src[start + base + li];
            float e = als[(size_t)s_l * 4 + head] + aldv;
            w_l = __expf(lrelu(e));
            wsum += w_l;
        }
        for (int e = 0; e < cnt; ++e) {
            const int s = __shfl(s_l, grpBase + e);
            const float a = __shfl(w_l, grpBase + e);
            short8 v = *(const short8*)(hfeat + (size_t)s * 512 + lane * 8);
            #pragma unroll
            for (int j = 0; j < 8; ++j) acc[j] += a * bf2f((unsigned int)(unsigned short)v[j]);
        }
    }

    #pragma unroll
    for (int off = 8; off >= 1; off >>= 1) wsum += __shfl_xor(wsum, off);
    const float sc = (deg > 0) ? 1.f / wsum : 0.f;

    float ov[8];
    #pragma unroll
    for (int j = 0; j < 8; ++j) {
        float o = acc[j] * sc + bias[lane * 8 + j];
        ov[j] = o > 0.f ? o : expm1f(o);
    }
    short8 v;
    #pragma unroll
    for (int j = 0; j < 8; ++j) v[j] = (short)f2bf(ov[j]);
    *(short8*)&out[(size_t)n * 512 + lane * 8] = v;
}

// ---------------- fused gather (H=1): weights in-loop, quarter-wave --------

__global__ __launch_bounds__(256) void gather1f_kernel(
    const unsigned short* __restrict__ hfeat,   // [N, 128] bf16
    const float* __restrict__ als, const float* __restrict__ ald,
    const int* __restrict__ row_ptr, const int* __restrict__ csr_src,
    const float* __restrict__ bias, float* __restrict__ out, int n_nodes)
{
    const int lane = threadIdx.x & 63;
    const int wv = threadIdx.x >> 6;
    const int n = blockIdx.x * 4 + wv;
    if (n >= n_nodes) return;
    const int qid = lane >> 4;       // quarter 0..3 = edge slot
    const int ql = lane & 15;        // 16B slot within row

    const int start = row_ptr[n];
    const int deg = row_ptr[n + 1] - start;
    const float aldv = ald[n];

    float acc[8] = {};
    float wsum = 0.f;
    for (int base = 0; base < deg; base += 64) {
        const int cnt = min(64, deg - base);
        int s_l = 0; float w_l = 0.f;
        if (lane < cnt) {
            s_l = csr_src[start + base + lane];
            float e = als[s_l] + aldv;
            w_l = __expf(lrelu(e));
            wsum += w_l;
        }
        for (int e = 0; e < cnt; e += 4) {
            const int idx = e + qid;
            const int idxc = idx < cnt ? idx : 0;
            const int s = __shfl(s_l, idxc);
            const float aw = __shfl(w_l, idxc);
            const float a = idx < cnt ? aw : 0.f;
            short8 v = *(const short8*)(hfeat + (size_t)s * 128 + ql * 8);
            #pragma unroll
            for (int j = 0; j < 8; ++j) acc[j] += a * bf2f((unsigned int)(unsigned short)v[j]);
        }
    }

    #pragma unroll
    for (int off = 32; off >= 1; off >>= 1) wsum += __shfl_xor(wsum, off);
    const float sc = (deg > 0) ? 1.f / wsum : 0.f;

    #pragma unroll
    for (int j = 0; j < 8; ++j) {
        acc[j] += __shfl_xor(acc[j], 16);
        acc[j] += __shfl_xor(acc[j], 32);
    }

    if (qid == 0) {
        float tmp[8];
        #pragma unroll
        for (int j = 0; j < 8; ++j) {
            float o = acc[j] * sc + bias[ql * 8 + j];
            tmp[j] = o > 0.f ? o : expm1f(o);
        }
        float4 o0 = {tmp[0], tmp[1], tmp[2], tmp[3]};
        float4 o1 = {tmp[4], tmp[5], tmp[6], tmp[7]};
        float* op = out + (size_t)n * 128 + ql * 8;
        *(float4*)op = o0;
        *(float4*)(op + 4) = o1;
    }
}

// ---------------------------------------------------------------------------

extern "C" void kernel_launch(void* const* d_in, const int* in_sizes, int n_in,
                              void* d_out, int out_size, void* d_ws, size_t ws_size,
                              hipStream_t stream) {
    const float* x   = (const float*)d_in[0];
    const int*   ei  = (const int*)d_in[1];
    const float* W1  = (const float*)d_in[2];
    const float* as1 = (const float*)d_in[3];
    const float* ad1 = (const float*)d_in[4];
    const float* b1  = (const float*)d_in[5];
    const float* W2  = (const float*)d_in[6];
    const float* as2 = (const float*)d_in[7];
    const float* ad2 = (const float*)d_in[8];
    const float* b2  = (const float*)d_in[9];
    const float* W3  = (const float*)d_in[10];
    const float* as3 = (const float*)d_in[11];
    const float* ad3 = (const float*)d_in[12];
    const float* b3  = (const float*)d_in[13];

    const int N = in_sizes[0] / 64;      // 50000
    const int E = in_sizes[1] / 2;       // 400000
    const int HC = 512;

    const int* src = ei;
    const int* dst = ei + E;

    size_t off = 0;
    auto carve = [&](size_t bytes) -> void* {
        void* p = (char*)d_ws + off;
        off += (bytes + 255) & ~(size_t)255;
        return p;
    };
    unsigned short* x_bf    = (unsigned short*)carve((size_t)MPAD * 64 * 2);
    unsigned short* feat_bf = (unsigned short*)carve((size_t)MPAD * HC * 2);
    unsigned short* h_bf    = (unsigned short*)carve((size_t)N * HC * 2);
    unsigned short* xagg    = (unsigned short*)carve((size_t)MPAD * 256 * 2);
    unsigned short* W1t     = (unsigned short*)carve((size_t)512 * 64 * 2);
    unsigned short* W2t     = (unsigned short*)carve((size_t)512 * 512 * 2);
    unsigned short* W3t     = (unsigned short*)carve((size_t)128 * 512 * 2);
    float* stats  = (float*)carve((size_t)N * 8 * sizeof(float));   // als|ald
    float* als    = stats;
    float* ald    = stats + (size_t)N * 4;
    float* ws     = (float*)carve(512 * sizeof(float) * 2);
    int*   counts = (int*)carve((size_t)N * sizeof(int));
    int*   row_ptr= (int*)carve((size_t)(N + 1) * sizeof(int));
    int*   cursor = (int*)carve((size_t)N * sizeof(int));
    int*   csr_src= (int*)carve((size_t)E * sizeof(int));
    int*   partial= (int*)carve(64 * sizeof(int));
    (void)ws_size;

    const int nb = (N + 1023) / 1024;    // 49 <= 64
    const int prepTotal = N * 64 + 64 * 512 + 512 * 512 + 512 * 128 + N + 256;

    // ---- prep (casts + transposes + counts zero + ws fold) ----
    prep_kernel<<<(prepTotal + 255) / 256, 256, 0, stream>>>(
        x, W1, W2, W3, as1, ad1, x_bf, W1t, W2t, W3t, counts, ws, N);

    // ---- CSR build ----
    count_deg_kernel<<<(E + 255) / 256, 256, 0, stream>>>(dst, counts, E);
    scan1_kernel<<<nb, 1024, 0, stream>>>(counts, row_ptr, partial, N);
    scan3c_kernel<<<nb, 1024, 0, stream>>>(row_ptr, partial, counts, cursor, N, nb);
    fill_csr_kernel<<<(E + 255) / 256, 256, 0, stream>>>(src, dst, cursor, csr_src, E);

    const int rowTiles = (N + 127) / 128;   // 391
    const int aggBlocks = (N + 3) / 4;

    // ---- layer 1 (aggregate x, then transform) ----
    als1_kernel<<<aggBlocks, 256, 0, stream>>>(x, ws, als, ald, N);
    gatherx_kernel<<<aggBlocks, 256, 0, stream>>>(x_bf, als, ald, row_ptr, csr_src, xagg, N);
    gemm_out_kernel<<<dim3(4, rowTiles), 256, 0, stream>>>(xagg, W1t, b1, feat_bf, N);

    // ---- layer 2 ----
    gemm_mfma_kernel<<<dim3(4, rowTiles), 256, 0, stream>>>(feat_bf, W2t, h_bf, as2, ad2,
                                                            als, ald, N, 512, 512, 4);
    gather4f_kernel<<<aggBlocks, 256, 0, stream>>>(h_bf, als, ald, row_ptr, csr_src,
                                                   b2, feat_bf, N);

    // ---- layer 3 ----
    gemm_mfma_kernel<<<dim3(1, rowTiles), 256, 0, stream>>>(feat_bf, W3t, h_bf, as3, ad3,
                                                            als, ald, N, 128, 512, 1);
    gather1f_kernel<<<aggBlocks, 256, 0, stream>>>(h_bf, als, ald, row_ptr, csr_src,
                                                   b3, (float*)d_out, N);
}